// Round 8
// baseline (392.919 us; speedup 1.0000x reference)
//
#include <hip/hip_runtime.h>

#define Bn 4
#define Tn 8192
#define Dn 512
#define GC 512
#define NG 16
#define ALPHAc 0.03f

typedef unsigned short u16;
typedef short bf8_t __attribute__((ext_vector_type(8)));
typedef float f4_t  __attribute__((ext_vector_type(4)));
typedef u16 us8_t __attribute__((ext_vector_type(8)));
typedef u16 us4_t __attribute__((ext_vector_type(4)));

#define MFMA16(a,b,c) __builtin_amdgcn_mfma_f32_16x16x32_bf16((a),(b),(c),0,0,0)

__device__ __forceinline__ u16 f2bf(float f) {
  union { float f; unsigned u; } v; v.f = f;
  unsigned r = v.u + 0x7fffu + ((v.u >> 16) & 1u);
  return (u16)(r >> 16);
}
__device__ __forceinline__ float bf2f(u16 h) {
  union { unsigned u; float f; } v; v.u = ((unsigned)h) << 16;
  return v.f;
}

// ---------------- fp32 -> bf16 convert ----------------
__global__ __launch_bounds__(256) void k_convert(const float* __restrict__ src,
                                                 u16* __restrict__ dst, int n4) {
  int i = blockIdx.x * 256 + threadIdx.x;
  if (i >= n4) return;
  float4 v = ((const float4*)src)[i];
  us4_t o = { f2bf(v.x), f2bf(v.y), f2bf(v.z), f2bf(v.w) };
  ((us4_t*)dst)[i] = o;
}

// ---------------- transpose with shift: wkT[b][e][t] = out_bf[b, t-1, e] ----------------
__global__ __launch_bounds__(256) void k_wkT(const u16* __restrict__ src,
                                             u16* __restrict__ dst) {
  __shared__ u16 T[128*129];
  const int tid = threadIdx.x;
  const int t0 = blockIdx.x * 128, e0 = blockIdx.y * 128;
  const int b = blockIdx.z;
  const size_t bT = (size_t)b * Tn;
#pragma unroll
  for (int i = 0; i < 8; ++i) {
    int slot = i*256 + tid;
    int row = slot >> 4, c8 = (slot & 15) << 3;
    int tg = t0 + row - 1;
    us8_t v8 = {0,0,0,0,0,0,0,0};
    if (tg >= 0) v8 = *(const us8_t*)&src[(bT + tg)*Dn + e0 + c8];
#pragma unroll
    for (int k = 0; k < 8; ++k) T[row*129 + c8 + k] = v8[k];
  }
  __syncthreads();
#pragma unroll
  for (int i = 0; i < 8; ++i) {
    int slot = i*256 + tid;
    int e = slot >> 4, t8 = (slot & 15) << 3;
    us8_t o;
#pragma unroll
    for (int k = 0; k < 8; ++k) o[k] = T[(t8 + k)*129 + e];
    *(us8_t*)&dst[((size_t)b*Dn + e0 + e)*Tn + t0 + t8] = o;
  }
}

// ---------------- K1: vT[b][d][t] = (out @ w_write^T)^T  (bf16) ----------------
__global__ __launch_bounds__(256) void k_gemm_v(const u16* __restrict__ A,
                                                const u16* __restrict__ Bm,
                                                u16* __restrict__ vT) {
  __shared__ u16 lds[128*72*2];
  u16* As = lds;
  u16* Bs = lds + 128*72;
  const int tid = threadIdx.x;
  const int lane = tid & 63, w = tid >> 6;
  const int g = lane >> 4, lr = lane & 15;
  const int m0 = blockIdx.y * 128, n0 = blockIdx.x * 128;
  const int wm = (w >> 1) * 64, wn = (w & 1) * 64;
  f4_t acc[4][4];
#pragma unroll
  for (int i = 0; i < 4; ++i)
#pragma unroll
    for (int j = 0; j < 4; ++j) acc[i][j] = (f4_t){0.f, 0.f, 0.f, 0.f};

  for (int kb = 0; kb < 8; ++kb) {
    const int k0 = kb * 64;
    __syncthreads();
#pragma unroll
    for (int i = 0; i < 8; ++i) {
      int slot = i * 256 + tid;
      int r = slot >> 4, c4 = (slot & 15) << 2;
      *(us4_t*)&As[r*72 + c4] = *(const us4_t*)&A[(m0 + r)*Dn + k0 + c4];
      *(us4_t*)&Bs[r*72 + c4] = *(const us4_t*)&Bm[(n0 + r)*Dn + k0 + c4];
    }
    __syncthreads();
#pragma unroll
    for (int kk = 0; kk < 2; ++kk) {
      const int co = kk*32 + g*8;
      bf8_t a[4], b[4];
#pragma unroll
      for (int mf = 0; mf < 4; ++mf) a[mf] = *(const bf8_t*)&As[(wm + mf*16 + lr)*72 + co];
#pragma unroll
      for (int nf = 0; nf < 4; ++nf) b[nf] = *(const bf8_t*)&Bs[(wn + nf*16 + lr)*72 + co];
#pragma unroll
      for (int mf = 0; mf < 4; ++mf)
#pragma unroll
        for (int nf = 0; nf < 4; ++nf)
          acc[mf][nf] = MFMA16(a[mf], b[nf], acc[mf][nf]);
    }
  }
  __syncthreads();
  u16* Cs = lds;  // [128 d][136 t]
#pragma unroll
  for (int mf = 0; mf < 4; ++mf)
#pragma unroll
    for (int nf = 0; nf < 4; ++nf)
#pragma unroll
      for (int r = 0; r < 4; ++r)
        Cs[(wn + nf*16 + lr)*136 + (wm + mf*16 + g*4 + r)] = f2bf(acc[mf][nf][r]);
  __syncthreads();
  const int b = m0 >> 13;
  const int tt0 = m0 & 8191;
#pragma unroll
  for (int i = 0; i < 8; ++i) {
    int slot = i * 256 + tid;
    int d = slot >> 4, t8 = (slot & 15) << 3;
    *(us8_t*)&vT[((size_t)b*Dn + n0 + d)*Tn + tt0 + t8] = *(const us8_t*)&Cs[d*136 + t8];
  }
}

// ---------------- K2: U_g[d][e] = sum_t vT[d][t]*gw(t)*wkT[e][t]  (bf16 out) ----------------
__global__ __launch_bounds__(256) void k_gemm_u(const u16* __restrict__ vT,
                                                const u16* __restrict__ wkT,
                                                u16* __restrict__ U,
                                                const float* __restrict__ decay) {
  __shared__ u16 lds[128*72*2];
  u16* As = lds;
  u16* Bs = lds + 128*72;
  const int tid = threadIdx.x;
  const int lane = tid & 63, w = tid >> 6;
  const int g = lane >> 4, lr = lane & 15;
  const int d0 = blockIdx.y * 128, e0 = blockIdx.x * 128;
  const int bg = blockIdx.z;
  const int b = bg >> 4, gg = bg & 15;
  const int wm = (w >> 1) * 64, wn = (w & 1) * 64;
  const float gamma = 1.f / (1.f + __builtin_expf(-decay[0]));
  const float l2g = __builtin_log2f(gamma);
  const float ginv = __builtin_exp2f(-l2g);
  const size_t kbase = (size_t)gg * GC;
  f4_t acc[4][4];
#pragma unroll
  for (int i = 0; i < 4; ++i)
#pragma unroll
    for (int j = 0; j < 4; ++j) acc[i][j] = (f4_t){0.f, 0.f, 0.f, 0.f};

  for (int kb = 0; kb < 8; ++kb) {
    const int k0 = kb * 64;
    __syncthreads();
#pragma unroll
    for (int i = 0; i < 8; ++i) {
      int slot = i * 256 + tid;
      int r = slot >> 4, c4 = (slot & 15) << 2;
      us4_t av = *(const us4_t*)&vT[((size_t)b*Dn + d0 + r)*Tn + kbase + k0 + c4];
      float gw = __builtin_exp2f(l2g * (float)(GC - 1 - (k0 + c4)));
      us4_t ao;
      ao.x = f2bf(bf2f(av.x) * gw); gw *= ginv;
      ao.y = f2bf(bf2f(av.y) * gw); gw *= ginv;
      ao.z = f2bf(bf2f(av.z) * gw); gw *= ginv;
      ao.w = f2bf(bf2f(av.w) * gw);
      *(us4_t*)&As[r*72 + c4] = ao;
      *(us4_t*)&Bs[r*72 + c4] = *(const us4_t*)&wkT[((size_t)b*Dn + e0 + r)*Tn + kbase + k0 + c4];
    }
    __syncthreads();
#pragma unroll
    for (int kk = 0; kk < 2; ++kk) {
      const int co = kk*32 + g*8;
      bf8_t a[4], bb[4];
#pragma unroll
      for (int mf = 0; mf < 4; ++mf) a[mf] = *(const bf8_t*)&As[(wm + mf*16 + lr)*72 + co];
#pragma unroll
      for (int nf = 0; nf < 4; ++nf) bb[nf] = *(const bf8_t*)&Bs[(wn + nf*16 + lr)*72 + co];
#pragma unroll
      for (int mf = 0; mf < 4; ++mf)
#pragma unroll
        for (int nf = 0; nf < 4; ++nf)
          acc[mf][nf] = MFMA16(a[mf], bb[nf], acc[mf][nf]);
    }
  }
  const size_t ub = (size_t)bg * Dn * Dn;
#pragma unroll
  for (int mf = 0; mf < 4; ++mf)
#pragma unroll
    for (int nf = 0; nf < 4; ++nf)
#pragma unroll
      for (int r = 0; r < 4; ++r)
        U[ub + (size_t)(d0 + wm + mf*16 + g*4 + r)*Dn + e0 + wn + nf*16 + lr] = f2bf(acc[mf][nf][r]);
}

// ---------------- K3: 16-step scan over chunk totals -> Wb[b][g] (bf16, pre-update) ----------------
__global__ __launch_bounds__(256) void k_bscan(const u16* __restrict__ U,
                                               u16* __restrict__ Wb,
                                               const float* __restrict__ decay) {
  const int tid = threadIdx.x;
  const int d0 = blockIdx.x * 64, e0 = blockIdx.y * 64;
  const int b = blockIdx.z;
  const float gamma = 1.f / (1.f + __builtin_expf(-decay[0]));
  const float gCC = __builtin_exp2f(__builtin_log2f(gamma) * (float)GC);
  const int colb = (tid & 15) << 2;
  const int rowb = (tid >> 4) << 2;
  float st[4][4];
#pragma unroll
  for (int rr = 0; rr < 4; ++rr)
#pragma unroll
    for (int cc = 0; cc < 4; ++cc) st[rr][cc] = 0.f;

  for (int gg = 0; gg < NG; ++gg) {
    const size_t base = (size_t)(b*NG + gg) * Dn * Dn;
#pragma unroll
    for (int rr = 0; rr < 4; ++rr) {
      us4_t o = { f2bf(st[rr][0]), f2bf(st[rr][1]), f2bf(st[rr][2]), f2bf(st[rr][3]) };
      *(us4_t*)&Wb[base + (size_t)(d0 + rowb + rr)*Dn + e0 + colb] = o;
      us4_t u4 = *(const us4_t*)&U[base + (size_t)(d0 + rowb + rr)*Dn + e0 + colb];
      st[rr][0] = gCC*st[rr][0] + bf2f(u4.x);
      st[rr][1] = gCC*st[rr][1] + bf2f(u4.y);
      st[rr][2] = gCC*st[rr][2] + bf2f(u4.z);
      st[rr][3] = gCC*st[rr][3] + bf2f(u4.w);
    }
  }
}

// ---------------- K4: binter[t][d] = gamma^{tloc} * rk_g @ Wb_g^T  (bf16) ----------------
__global__ __launch_bounds__(256) void k_binter(const u16* __restrict__ out_bf,
                                                const u16* __restrict__ Wb,
                                                u16* __restrict__ binter,
                                                const float* __restrict__ decay) {
  __shared__ u16 lds[128*72*2];
  u16* As = lds;
  u16* Bs = lds + 128*72;
  const int tid = threadIdx.x;
  const int lane = tid & 63, w = tid >> 6;
  const int g = lane >> 4, lr = lane & 15;
  const int m0 = blockIdx.y * 128, n0 = blockIdx.x * 128;
  const int z = blockIdx.z;
  const int b = z / 15, gg = z % 15 + 1;
  const int wm = (w >> 1) * 64, wn = (w & 1) * 64;
  const float gamma = 1.f / (1.f + __builtin_expf(-decay[0]));
  const float l2g = __builtin_log2f(gamma);
  const size_t arow = (size_t)b*Tn + (size_t)gg*GC + m0;
  const size_t brow = (size_t)(b*NG + gg) * Dn * Dn;
  f4_t acc[4][4];
#pragma unroll
  for (int i = 0; i < 4; ++i)
#pragma unroll
    for (int j = 0; j < 4; ++j) acc[i][j] = (f4_t){0.f, 0.f, 0.f, 0.f};

  for (int kb = 0; kb < 8; ++kb) {
    const int k0 = kb * 64;
    __syncthreads();
#pragma unroll
    for (int i = 0; i < 8; ++i) {
      int slot = i * 256 + tid;
      int r = slot >> 4, c4 = (slot & 15) << 2;
      *(us4_t*)&As[r*72 + c4] = *(const us4_t*)&out_bf[(arow + r)*Dn + k0 + c4];
      *(us4_t*)&Bs[r*72 + c4] = *(const us4_t*)&Wb[brow + (size_t)(n0 + r)*Dn + k0 + c4];
    }
    __syncthreads();
#pragma unroll
    for (int kk = 0; kk < 2; ++kk) {
      const int co = kk*32 + g*8;
      bf8_t a[4], bb[4];
#pragma unroll
      for (int mf = 0; mf < 4; ++mf) a[mf] = *(const bf8_t*)&As[(wm + mf*16 + lr)*72 + co];
#pragma unroll
      for (int nf = 0; nf < 4; ++nf) bb[nf] = *(const bf8_t*)&Bs[(wn + nf*16 + lr)*72 + co];
#pragma unroll
      for (int mf = 0; mf < 4; ++mf)
#pragma unroll
        for (int nf = 0; nf < 4; ++nf)
          acc[mf][nf] = MFMA16(a[mf], bb[nf], acc[mf][nf]);
    }
  }
  __syncthreads();
  u16* Cs = lds;  // [128 t][136 d]
#pragma unroll
  for (int mf = 0; mf < 4; ++mf) {
#pragma unroll
    for (int r = 0; r < 4; ++r) {
      const float gp = __builtin_exp2f(l2g * (float)(m0 + wm + mf*16 + g*4 + r));
#pragma unroll
      for (int nf = 0; nf < 4; ++nf)
        Cs[(wm + mf*16 + g*4 + r)*136 + wn + nf*16 + lr] = f2bf(acc[mf][nf][r] * gp);
    }
  }
  __syncthreads();
#pragma unroll
  for (int i = 0; i < 8; ++i) {
    int slot = i * 256 + tid;
    int r = slot >> 4, c8 = (slot & 15) << 3;
    *(us8_t*)&binter[(arow + r)*Dn + n0 + c8] = *(const us8_t*)&Cs[r*136 + c8];
  }
}

// ---------------- K5: intra (within-512-chunk causal decay attention) + binter add ----------------
// grid (16 gg, 8 qt, 4 b): xcd = gg%8 -> per-XCD wk/vT reuse across qt + balanced load.
// 5-sync pipelined j-loop; rk in regs; LDS 79,872 B, 2 WG/CU.
__global__ __launch_bounds__(256, 2) void k_intra(const u16* __restrict__ out_bf,
                                                  const u16* __restrict__ vT,
                                                  const u16* __restrict__ binter,
                                                  u16* __restrict__ reads_bf,
                                                  const float* __restrict__ decay) {
  __shared__ u16 WKh[64*264];   // wk kv-block e-half [s][e]; also epilogue scratch
  __shared__ u16 VT4[256*72];   // v^T d-half [d][s]
  __shared__ u16 PS[64*72];     // P [t][s]
  const int tid = threadIdx.x;
  const int lane = tid & 63, w = tid >> 6;
  const int g = lane >> 4, lr = lane & 15;
  const int gg = blockIdx.x, qt = blockIdx.y, b = blockIdx.z;
  const float gamma = 1.f / (1.f + __builtin_expf(-decay[0]));
  const float l2g = __builtin_log2f(gamma);
  const size_t bT = (size_t)b * Tn;
  const size_t rowbase = bT + (size_t)gg*GC + qt*64;

  // rk row (w*16+lr): 16 x 16B frags in registers, loaded once
  bf8_t rk[16];
#pragma unroll
  for (int kk = 0; kk < 16; ++kk)
    rk[kk] = *(const bf8_t*)&out_bf[(rowbase + w*16 + lr)*Dn + kk*32 + g*8];

  f4_t acc[2][4][4];  // [d-half][mf=d][nf=t]
#pragma unroll
  for (int h = 0; h < 2; ++h)
#pragma unroll
    for (int i = 0; i < 4; ++i)
#pragma unroll
      for (int j = 0; j < 4; ++j) acc[h][i][j] = (f4_t){0.f, 0.f, 0.f, 0.f};

  // ---- staging helpers (inlined) ----
  // stage wk e-half 'eh' of kv-block j into WKh
#define STAGE_WK(JJ, EH)                                                      \
  {                                                                           \
    const int sgs = gg*GC + (JJ)*64;                                          \
    _Pragma("unroll")                                                         \
    for (int i = 0; i < 8; ++i) {                                             \
      int slot = i*256 + tid;                                                 \
      int s = slot >> 5, c8 = (slot & 31) << 3;                               \
      us8_t v8 = {0,0,0,0,0,0,0,0};                                           \
      int wr = sgs + s - 1;                                                   \
      if (wr >= 0) v8 = *(const us8_t*)&out_bf[(bT + wr)*Dn + (EH)*256 + c8]; \
      *(us8_t*)&WKh[s*264 + c8] = v8;                                         \
    }                                                                         \
  }
  // stage v^T d-half 'dh' of kv-block j into VT4
#define STAGE_VT(JJ, DH)                                                      \
  {                                                                           \
    const int sgs = gg*GC + (JJ)*64;                                          \
    _Pragma("unroll")                                                         \
    for (int i = 0; i < 8; ++i) {                                             \
      int slot = i*256 + tid;                                                 \
      int d = slot >> 3, c8 = (slot & 7) << 3;                                \
      *(us8_t*)&VT4[d*72 + c8] =                                              \
        *(const us8_t*)&vT[((size_t)b*Dn + (DH)*256 + d)*Tn + sgs + c8];      \
    }                                                                         \
  }

  // prologue: stage wk-eh0 of j=0
  STAGE_WK(0, 0);
  __syncthreads();

  for (int j = 0; j <= qt; ++j) {
    f4_t sacc[4];
#pragma unroll
    for (int i = 0; i < 4; ++i) sacc[i] = (f4_t){0.f, 0.f, 0.f, 0.f};

    // QKT over eh=0 (WKh pre-staged)
#pragma unroll
    for (int kk = 0; kk < 8; ++kk) {
      const int co = kk*32 + g*8;
#pragma unroll
      for (int nf = 0; nf < 4; ++nf) {
        bf8_t bb = *(const bf8_t*)&WKh[(nf*16 + lr)*264 + co];
        sacc[nf] = MFMA16(rk[kk], bb, sacc[nf]);
      }
    }
    __syncthreads();                    // (a) QKT-eh0 reads done
    STAGE_WK(j, 1);
    STAGE_VT(j, 0);
    __syncthreads();                    // (b) wk-eh1 + vT-dh0 visible
    // QKT over eh=1
#pragma unroll
    for (int kk = 0; kk < 8; ++kk) {
      const int co = kk*32 + g*8;
#pragma unroll
      for (int nf = 0; nf < 4; ++nf) {
        bf8_t bb = *(const bf8_t*)&WKh[(nf*16 + lr)*264 + co];
        sacc[nf] = MFMA16(rk[8 + kk], bb, sacc[nf]);
      }
    }
    // mask+decay -> PS[t][s]; thread holds t = w*16+g*4+r, s = nf*16+lr
#pragma unroll
    for (int nf = 0; nf < 4; ++nf) {
#pragma unroll
      for (int r = 0; r < 4; ++r) {
        int tt = w*16 + g*4 + r;
        int ss = nf*16 + lr;
        float df = (float)((qt - j)*64 + tt - ss - 1);
        float mval = (j < qt || tt > ss) ? __builtin_exp2f(l2g * df) : 0.f;
        PS[tt*72 + ss] = f2bf(sacc[nf][r] * mval);
      }
    }
    __syncthreads();                    // (c) PS + vT-dh0 ready
    // PV d-half 0
#pragma unroll
    for (int kk = 0; kk < 2; ++kk) {
      const int co = kk*32 + g*8;
      bf8_t a[4], bb[4];
#pragma unroll
      for (int mf = 0; mf < 4; ++mf) a[mf] = *(const bf8_t*)&VT4[(w*64 + mf*16 + lr)*72 + co];
#pragma unroll
      for (int nf = 0; nf < 4; ++nf) bb[nf] = *(const bf8_t*)&PS[(nf*16 + lr)*72 + co];
#pragma unroll
      for (int mf = 0; mf < 4; ++mf)
#pragma unroll
        for (int nf = 0; nf < 4; ++nf)
          acc[0][mf][nf] = MFMA16(a[mf], bb[nf], acc[0][mf][nf]);
    }
    __syncthreads();                    // (d) PV-dh0 reads done
    STAGE_VT(j, 1);
    if (j < qt) STAGE_WK(j + 1, 0);     // prefetch next kv-block's wk-eh0
    __syncthreads();                    // (e) vT-dh1 (+ next wk) visible
    // PV d-half 1
#pragma unroll
    for (int kk = 0; kk < 2; ++kk) {
      const int co = kk*32 + g*8;
      bf8_t a[4], bb[4];
#pragma unroll
      for (int mf = 0; mf < 4; ++mf) a[mf] = *(const bf8_t*)&VT4[(w*64 + mf*16 + lr)*72 + co];
#pragma unroll
      for (int nf = 0; nf < 4; ++nf) bb[nf] = *(const bf8_t*)&PS[(nf*16 + lr)*72 + co];
#pragma unroll
      for (int mf = 0; mf < 4; ++mf)
#pragma unroll
        for (int nf = 0; nf < 4; ++nf)
          acc[1][mf][nf] = MFMA16(a[mf], bb[nf], acc[1][mf][nf]);
    }
  }
#undef STAGE_WK
#undef STAGE_VT

  // epilogue per d-half: transpose acc via WKh -> [t][d], add binter, store
#pragma unroll
  for (int dh2 = 0; dh2 < 2; ++dh2) {
    __syncthreads();
#pragma unroll
    for (int mf = 0; mf < 4; ++mf)
#pragma unroll
      for (int nf = 0; nf < 4; ++nf)
#pragma unroll
        for (int r = 0; r < 4; ++r)
          WKh[(nf*16 + lr)*264 + w*64 + mf*16 + g*4 + r] = f2bf(acc[dh2][mf][nf][r]);
    __syncthreads();
#pragma unroll
    for (int i = 0; i < 8; ++i) {
      int slot = i*256 + tid;
      int t = slot >> 5, d8 = (slot & 31) << 3;
      us8_t ev = *(const us8_t*)&WKh[t*264 + d8];
      us8_t o;
      if (gg > 0) {
        us8_t bv = *(const us8_t*)&binter[(rowbase + t)*Dn + dh2*256 + d8];
#pragma unroll
        for (int k = 0; k < 8; ++k) o[k] = f2bf(bf2f(ev[k]) + bf2f(bv[k]));
      } else {
        o = ev;
      }
      *(us8_t*)&reads_bf[(rowbase + t)*Dn + dh2*256 + d8] = o;
    }
  }
}

// ---------------- K6: out = resid + alpha * (reads @ w_read^T) ----------------
__global__ __launch_bounds__(256) void k_final(const u16* __restrict__ A,
                                               const u16* __restrict__ Bm,
                                               const float* __restrict__ resid,
                                               float* __restrict__ Cout) {
  __shared__ u16 lds[128*72*2];
  u16* As = lds;
  u16* Bs = lds + 128*72;
  const int tid = threadIdx.x;
  const int lane = tid & 63, w = tid >> 6;
  const int g = lane >> 4, lr = lane & 15;
  const int m0 = blockIdx.y * 128, n0 = blockIdx.x * 128;
  const int wm = (w >> 1) * 64, wn = (w & 1) * 64;
  f4_t acc[4][4];
#pragma unroll
  for (int i = 0; i < 4; ++i)
#pragma unroll
    for (int j = 0; j < 4; ++j) acc[i][j] = (f4_t){0.f, 0.f, 0.f, 0.f};

  for (int kb = 0; kb < 8; ++kb) {
    const int k0 = kb * 64;
    __syncthreads();
#pragma unroll
    for (int i = 0; i < 8; ++i) {
      int slot = i * 256 + tid;
      int r = slot >> 4, c4 = (slot & 15) << 2;
      *(us4_t*)&As[r*72 + c4] = *(const us4_t*)&A[(m0 + r)*Dn + k0 + c4];
      *(us4_t*)&Bs[r*72 + c4] = *(const us4_t*)&Bm[(n0 + r)*Dn + k0 + c4];
    }
    __syncthreads();
#pragma unroll
    for (int kk = 0; kk < 2; ++kk) {
      const int co = kk*32 + g*8;
      bf8_t a[4], b[4];
#pragma unroll
      for (int mf = 0; mf < 4; ++mf) a[mf] = *(const bf8_t*)&As[(wm + mf*16 + lr)*72 + co];
#pragma unroll
      for (int nf = 0; nf < 4; ++nf) b[nf] = *(const bf8_t*)&Bs[(wn + nf*16 + lr)*72 + co];
#pragma unroll
      for (int mf = 0; mf < 4; ++mf)
#pragma unroll
        for (int nf = 0; nf < 4; ++nf)
          acc[mf][nf] = MFMA16(a[mf], b[nf], acc[mf][nf]);
    }
  }
#pragma unroll
  for (int mf = 0; mf < 4; ++mf)
#pragma unroll
    for (int nf = 0; nf < 4; ++nf)
#pragma unroll
      for (int r = 0; r < 4; ++r) {
        int row = m0 + wm + mf*16 + g*4 + r;
        int col = n0 + wn + nf*16 + lr;
        int idx = row * Dn + col;
        Cout[idx] = resid[idx] + ALPHAc * acc[mf][nf][r];
      }
}

extern "C" void kernel_launch(void* const* d_in, const int* in_sizes, int n_in,
                              void* d_out, int out_size, void* d_ws, size_t ws_size,
                              hipStream_t stream) {
  const float* out_f   = (const float*)d_in[0];
  const float* w_write = (const float*)d_in[1];
  const float* w_read  = (const float*)d_in[2];
  const float* decay   = (const float*)d_in[3];
  float* outp = (float*)d_out;

  char* ws = (char*)d_ws;
  // NON-ALIASED layout (replay-overlap safe). Total 235,929,600 B.
  u16*   out_bf = (u16*)(ws);
  u16*   wkT    = (u16*)(ws + (size_t)33554432);
  u16*   vT     = (u16*)(ws + (size_t)67108864);
  u16*   wwt_bf = (u16*)(ws + (size_t)100663296);
  u16*   wrd_bf = (u16*)(ws + (size_t)101187584);
  u16*   U      = (u16*)(ws + (size_t)101711872);
  u16*   binter = (u16*)(ws + (size_t)135266304);
  u16*   reads  = (u16*)(ws + (size_t)168820736);
  u16*   Wb     = (u16*)(ws + (size_t)202375168);

  k_convert<<<16384, 256, 0, stream>>>(out_f, out_bf, 4194304);
  k_convert<<<256, 256, 0, stream>>>(w_write, wwt_bf, 65536);
  k_convert<<<256, 256, 0, stream>>>(w_read, wrd_bf, 65536);
  k_wkT<<<dim3(64, 4, 4), 256, 0, stream>>>(out_bf, wkT);
  k_gemm_v<<<dim3(4, 256), 256, 0, stream>>>(out_bf, wwt_bf, vT);
  k_gemm_u<<<dim3(4, 4, 64), 256, 0, stream>>>(vT, wkT, U, decay);
  k_bscan<<<dim3(8, 8, 4), 256, 0, stream>>>(U, Wb, decay);
  k_binter<<<dim3(4, 4, 60), 256, 0, stream>>>(out_bf, Wb, binter, decay);
  k_intra<<<dim3(16, 8, 4), 256, 0, stream>>>(out_bf, vT, binter, reads, decay);
  k_final<<<dim3(4, 256), 256, 0, stream>>>(reads, wrd_bf, out_f, outp);
}

// Round 9
// 339.369 us; speedup vs baseline: 1.1578x; 1.1578x over previous
//
#include <hip/hip_runtime.h>

#define Bn 4
#define Tn 8192
#define Dn 512
#define GC 512
#define NG 16
#define ALPHAc 0.03f

typedef unsigned short u16;
typedef short bf8_t __attribute__((ext_vector_type(8)));
typedef float f4_t  __attribute__((ext_vector_type(4)));
typedef u16 us8_t __attribute__((ext_vector_type(8)));
typedef u16 us4_t __attribute__((ext_vector_type(4)));

#define MFMA16(a,b,c) __builtin_amdgcn_mfma_f32_16x16x32_bf16((a),(b),(c),0,0,0)

__device__ __forceinline__ u16 f2bf(float f) {
  union { float f; unsigned u; } v; v.f = f;
  unsigned r = v.u + 0x7fffu + ((v.u >> 16) & 1u);
  return (u16)(r >> 16);
}
__device__ __forceinline__ float bf2f(u16 h) {
  union { unsigned u; float f; } v; v.u = ((unsigned)h) << 16;
  return v.f;
}

// ---------------- fp32 -> bf16 convert ----------------
__global__ __launch_bounds__(256) void k_convert(const float* __restrict__ src,
                                                 u16* __restrict__ dst, int n4) {
  int i = blockIdx.x * 256 + threadIdx.x;
  if (i >= n4) return;
  float4 v = ((const float4*)src)[i];
  us4_t o = { f2bf(v.x), f2bf(v.y), f2bf(v.z), f2bf(v.w) };
  ((us4_t*)dst)[i] = o;
}

// ---------------- transpose with shift: wkT[b][e][t] = out_bf[b, t-1, e] ----------------
__global__ __launch_bounds__(256) void k_wkT(const u16* __restrict__ src,
                                             u16* __restrict__ dst) {
  __shared__ u16 T[128*129];
  const int tid = threadIdx.x;
  const int t0 = blockIdx.x * 128, e0 = blockIdx.y * 128;
  const int b = blockIdx.z;
  const size_t bT = (size_t)b * Tn;
#pragma unroll
  for (int i = 0; i < 8; ++i) {
    int slot = i*256 + tid;
    int row = slot >> 4, c8 = (slot & 15) << 3;
    int tg = t0 + row - 1;
    us8_t v8 = {0,0,0,0,0,0,0,0};
    if (tg >= 0) v8 = *(const us8_t*)&src[(bT + tg)*Dn + e0 + c8];
#pragma unroll
    for (int k = 0; k < 8; ++k) T[row*129 + c8 + k] = v8[k];
  }
  __syncthreads();
#pragma unroll
  for (int i = 0; i < 8; ++i) {
    int slot = i*256 + tid;
    int e = slot >> 4, t8 = (slot & 15) << 3;
    us8_t o;
#pragma unroll
    for (int k = 0; k < 8; ++k) o[k] = T[(t8 + k)*129 + e];
    *(us8_t*)&dst[((size_t)b*Dn + e0 + e)*Tn + t0 + t8] = o;
  }
}

// ---------------- K1: vT[b][d][t] = (out @ w_write^T)^T  (bf16) ----------------
__global__ __launch_bounds__(256) void k_gemm_v(const u16* __restrict__ A,
                                                const u16* __restrict__ Bm,
                                                u16* __restrict__ vT) {
  __shared__ u16 lds[128*72*2];
  u16* As = lds;
  u16* Bs = lds + 128*72;
  const int tid = threadIdx.x;
  const int lane = tid & 63, w = tid >> 6;
  const int g = lane >> 4, lr = lane & 15;
  const int m0 = blockIdx.y * 128, n0 = blockIdx.x * 128;
  const int wm = (w >> 1) * 64, wn = (w & 1) * 64;
  f4_t acc[4][4];
#pragma unroll
  for (int i = 0; i < 4; ++i)
#pragma unroll
    for (int j = 0; j < 4; ++j) acc[i][j] = (f4_t){0.f, 0.f, 0.f, 0.f};

  for (int kb = 0; kb < 8; ++kb) {
    const int k0 = kb * 64;
    __syncthreads();
#pragma unroll
    for (int i = 0; i < 8; ++i) {
      int slot = i * 256 + tid;
      int r = slot >> 4, c4 = (slot & 15) << 2;
      *(us4_t*)&As[r*72 + c4] = *(const us4_t*)&A[(m0 + r)*Dn + k0 + c4];
      *(us4_t*)&Bs[r*72 + c4] = *(const us4_t*)&Bm[(n0 + r)*Dn + k0 + c4];
    }
    __syncthreads();
#pragma unroll
    for (int kk = 0; kk < 2; ++kk) {
      const int co = kk*32 + g*8;
      bf8_t a[4], b[4];
#pragma unroll
      for (int mf = 0; mf < 4; ++mf) a[mf] = *(const bf8_t*)&As[(wm + mf*16 + lr)*72 + co];
#pragma unroll
      for (int nf = 0; nf < 4; ++nf) b[nf] = *(const bf8_t*)&Bs[(wn + nf*16 + lr)*72 + co];
#pragma unroll
      for (int mf = 0; mf < 4; ++mf)
#pragma unroll
        for (int nf = 0; nf < 4; ++nf)
          acc[mf][nf] = MFMA16(a[mf], b[nf], acc[mf][nf]);
    }
  }
  __syncthreads();
  u16* Cs = lds;  // [128 d][136 t]
#pragma unroll
  for (int mf = 0; mf < 4; ++mf)
#pragma unroll
    for (int nf = 0; nf < 4; ++nf)
#pragma unroll
      for (int r = 0; r < 4; ++r)
        Cs[(wn + nf*16 + lr)*136 + (wm + mf*16 + g*4 + r)] = f2bf(acc[mf][nf][r]);
  __syncthreads();
  const int b = m0 >> 13;
  const int tt0 = m0 & 8191;
#pragma unroll
  for (int i = 0; i < 8; ++i) {
    int slot = i * 256 + tid;
    int d = slot >> 4, t8 = (slot & 15) << 3;
    *(us8_t*)&vT[((size_t)b*Dn + n0 + d)*Tn + tt0 + t8] = *(const us8_t*)&Cs[d*136 + t8];
  }
}

// ---------------- K2: U_g[d][e] = sum_t vT[d][t]*gw(t)*wkT[e][t]  (bf16 out) ----------------
__global__ __launch_bounds__(256) void k_gemm_u(const u16* __restrict__ vT,
                                                const u16* __restrict__ wkT,
                                                u16* __restrict__ U,
                                                const float* __restrict__ decay) {
  __shared__ u16 lds[128*72*2];
  u16* As = lds;
  u16* Bs = lds + 128*72;
  const int tid = threadIdx.x;
  const int lane = tid & 63, w = tid >> 6;
  const int g = lane >> 4, lr = lane & 15;
  const int d0 = blockIdx.y * 128, e0 = blockIdx.x * 128;
  const int bg = blockIdx.z;
  const int b = bg >> 4, gg = bg & 15;
  const int wm = (w >> 1) * 64, wn = (w & 1) * 64;
  const float gamma = 1.f / (1.f + __builtin_expf(-decay[0]));
  const float l2g = __builtin_log2f(gamma);
  const float ginv = __builtin_exp2f(-l2g);
  const size_t kbase = (size_t)gg * GC;
  f4_t acc[4][4];
#pragma unroll
  for (int i = 0; i < 4; ++i)
#pragma unroll
    for (int j = 0; j < 4; ++j) acc[i][j] = (f4_t){0.f, 0.f, 0.f, 0.f};

  for (int kb = 0; kb < 8; ++kb) {
    const int k0 = kb * 64;
    __syncthreads();
#pragma unroll
    for (int i = 0; i < 8; ++i) {
      int slot = i * 256 + tid;
      int r = slot >> 4, c4 = (slot & 15) << 2;
      us4_t av = *(const us4_t*)&vT[((size_t)b*Dn + d0 + r)*Tn + kbase + k0 + c4];
      float gw = __builtin_exp2f(l2g * (float)(GC - 1 - (k0 + c4)));
      us4_t ao;
      ao.x = f2bf(bf2f(av.x) * gw); gw *= ginv;
      ao.y = f2bf(bf2f(av.y) * gw); gw *= ginv;
      ao.z = f2bf(bf2f(av.z) * gw); gw *= ginv;
      ao.w = f2bf(bf2f(av.w) * gw);
      *(us4_t*)&As[r*72 + c4] = ao;
      *(us4_t*)&Bs[r*72 + c4] = *(const us4_t*)&wkT[((size_t)b*Dn + e0 + r)*Tn + kbase + k0 + c4];
    }
    __syncthreads();
#pragma unroll
    for (int kk = 0; kk < 2; ++kk) {
      const int co = kk*32 + g*8;
      bf8_t a[4], bb[4];
#pragma unroll
      for (int mf = 0; mf < 4; ++mf) a[mf] = *(const bf8_t*)&As[(wm + mf*16 + lr)*72 + co];
#pragma unroll
      for (int nf = 0; nf < 4; ++nf) bb[nf] = *(const bf8_t*)&Bs[(wn + nf*16 + lr)*72 + co];
#pragma unroll
      for (int mf = 0; mf < 4; ++mf)
#pragma unroll
        for (int nf = 0; nf < 4; ++nf)
          acc[mf][nf] = MFMA16(a[mf], bb[nf], acc[mf][nf]);
    }
  }
  const size_t ub = (size_t)bg * Dn * Dn;
#pragma unroll
  for (int mf = 0; mf < 4; ++mf)
#pragma unroll
    for (int nf = 0; nf < 4; ++nf)
#pragma unroll
      for (int r = 0; r < 4; ++r)
        U[ub + (size_t)(d0 + wm + mf*16 + g*4 + r)*Dn + e0 + wn + nf*16 + lr] = f2bf(acc[mf][nf][r]);
}

// ---------------- K3: 16-step scan over chunk totals -> Wb[b][g] (bf16, pre-update) ----------------
__global__ __launch_bounds__(256) void k_bscan(const u16* __restrict__ U,
                                               u16* __restrict__ Wb,
                                               const float* __restrict__ decay) {
  const int tid = threadIdx.x;
  const int d0 = blockIdx.x * 64, e0 = blockIdx.y * 64;
  const int b = blockIdx.z;
  const float gamma = 1.f / (1.f + __builtin_expf(-decay[0]));
  const float gCC = __builtin_exp2f(__builtin_log2f(gamma) * (float)GC);
  const int colb = (tid & 15) << 2;
  const int rowb = (tid >> 4) << 2;
  float st[4][4];
#pragma unroll
  for (int rr = 0; rr < 4; ++rr)
#pragma unroll
    for (int cc = 0; cc < 4; ++cc) st[rr][cc] = 0.f;

  for (int gg = 0; gg < NG; ++gg) {
    const size_t base = (size_t)(b*NG + gg) * Dn * Dn;
#pragma unroll
    for (int rr = 0; rr < 4; ++rr) {
      us4_t o = { f2bf(st[rr][0]), f2bf(st[rr][1]), f2bf(st[rr][2]), f2bf(st[rr][3]) };
      *(us4_t*)&Wb[base + (size_t)(d0 + rowb + rr)*Dn + e0 + colb] = o;
      us4_t u4 = *(const us4_t*)&U[base + (size_t)(d0 + rowb + rr)*Dn + e0 + colb];
      st[rr][0] = gCC*st[rr][0] + bf2f(u4.x);
      st[rr][1] = gCC*st[rr][1] + bf2f(u4.y);
      st[rr][2] = gCC*st[rr][2] + bf2f(u4.z);
      st[rr][3] = gCC*st[rr][3] + bf2f(u4.w);
    }
  }
}

// ---------------- K4: binter[t][d] = gamma^{tloc} * rk_g @ Wb_g^T  (bf16) ----------------
__global__ __launch_bounds__(256) void k_binter(const u16* __restrict__ out_bf,
                                                const u16* __restrict__ Wb,
                                                u16* __restrict__ binter,
                                                const float* __restrict__ decay) {
  __shared__ u16 lds[128*72*2];
  u16* As = lds;
  u16* Bs = lds + 128*72;
  const int tid = threadIdx.x;
  const int lane = tid & 63, w = tid >> 6;
  const int g = lane >> 4, lr = lane & 15;
  const int m0 = blockIdx.y * 128, n0 = blockIdx.x * 128;
  const int z = blockIdx.z;
  const int b = z / 15, gg = z % 15 + 1;
  const int wm = (w >> 1) * 64, wn = (w & 1) * 64;
  const float gamma = 1.f / (1.f + __builtin_expf(-decay[0]));
  const float l2g = __builtin_log2f(gamma);
  const size_t arow = (size_t)b*Tn + (size_t)gg*GC + m0;
  const size_t brow = (size_t)(b*NG + gg) * Dn * Dn;
  f4_t acc[4][4];
#pragma unroll
  for (int i = 0; i < 4; ++i)
#pragma unroll
    for (int j = 0; j < 4; ++j) acc[i][j] = (f4_t){0.f, 0.f, 0.f, 0.f};

  for (int kb = 0; kb < 8; ++kb) {
    const int k0 = kb * 64;
    __syncthreads();
#pragma unroll
    for (int i = 0; i < 8; ++i) {
      int slot = i * 256 + tid;
      int r = slot >> 4, c4 = (slot & 15) << 2;
      *(us4_t*)&As[r*72 + c4] = *(const us4_t*)&out_bf[(arow + r)*Dn + k0 + c4];
      *(us4_t*)&Bs[r*72 + c4] = *(const us4_t*)&Wb[brow + (size_t)(n0 + r)*Dn + k0 + c4];
    }
    __syncthreads();
#pragma unroll
    for (int kk = 0; kk < 2; ++kk) {
      const int co = kk*32 + g*8;
      bf8_t a[4], bb[4];
#pragma unroll
      for (int mf = 0; mf < 4; ++mf) a[mf] = *(const bf8_t*)&As[(wm + mf*16 + lr)*72 + co];
#pragma unroll
      for (int nf = 0; nf < 4; ++nf) bb[nf] = *(const bf8_t*)&Bs[(wn + nf*16 + lr)*72 + co];
#pragma unroll
      for (int mf = 0; mf < 4; ++mf)
#pragma unroll
        for (int nf = 0; nf < 4; ++nf)
          acc[mf][nf] = MFMA16(a[mf], bb[nf], acc[mf][nf]);
    }
  }
  __syncthreads();
  u16* Cs = lds;  // [128 t][136 d]
#pragma unroll
  for (int mf = 0; mf < 4; ++mf) {
#pragma unroll
    for (int r = 0; r < 4; ++r) {
      const float gp = __builtin_exp2f(l2g * (float)(m0 + wm + mf*16 + g*4 + r));
#pragma unroll
      for (int nf = 0; nf < 4; ++nf)
        Cs[(wm + mf*16 + g*4 + r)*136 + wn + nf*16 + lr] = f2bf(acc[mf][nf][r] * gp);
    }
  }
  __syncthreads();
#pragma unroll
  for (int i = 0; i < 8; ++i) {
    int slot = i * 256 + tid;
    int r = slot >> 4, c8 = (slot & 15) << 3;
    *(us8_t*)&binter[(arow + r)*Dn + n0 + c8] = *(const us8_t*)&Cs[r*136 + c8];
  }
}

// ---------------- K5: intra v3 — 2 barriers/j; wk LDS-staged, vT global frags ----------------
// grid (16 gg, 8 qt, 4 b); LDS 75,776 B; 2 WG/CU.
__global__ __launch_bounds__(256, 2) void k_intra(const u16* __restrict__ out_bf,
                                                  const u16* __restrict__ vT,
                                                  const u16* __restrict__ binter,
                                                  u16* __restrict__ reads_bf,
                                                  const float* __restrict__ decay) {
  __shared__ u16 WKh[64*520];   // wk block [s][e], full 512-e width; epilogue scratch
  __shared__ u16 PS[64*72];     // P [t][s]
  const int tid = threadIdx.x;
  const int lane = tid & 63, w = tid >> 6;
  const int g = lane >> 4, lr = lane & 15;
  const int gg = blockIdx.x, qt = blockIdx.y, b = blockIdx.z;
  const float gamma = 1.f / (1.f + __builtin_expf(-decay[0]));
  const float l2g = __builtin_log2f(gamma);
  const size_t bT = (size_t)b * Tn;
  const size_t rowbase = bT + (size_t)gg*GC + qt*64;

  // rk row (w*16+lr) in registers (A-operand of QKT), loaded once
  bf8_t rk[16];
#pragma unroll
  for (int kk = 0; kk < 16; ++kk)
    rk[kk] = *(const bf8_t*)&out_bf[(rowbase + w*16 + lr)*Dn + kk*32 + g*8];

  // per-lane vT base: row (w*64+lr), col gg*GC + g*8 (dh/mf/j/kk offsets added at use)
  const u16* vbase = vT + ((size_t)b*Dn + w*64 + lr)*Tn + (size_t)gg*GC + g*8;

  f4_t acc[2][4][4];  // [d-half][mf=d][nf=t]
#pragma unroll
  for (int h = 0; h < 2; ++h)
#pragma unroll
    for (int i = 0; i < 4; ++i)
#pragma unroll
      for (int j = 0; j < 4; ++j) acc[h][i][j] = (f4_t){0.f, 0.f, 0.f, 0.f};

  for (int j = 0; j <= qt; ++j) {
    const int sg0 = gg*GC + j*64;
    // stage full wk block [64 s][512 e] (shifted by 1, zero row s=-1)
#pragma unroll
    for (int i = 0; i < 16; ++i) {
      int slot = i*256 + tid;
      int s = slot >> 6, e8 = (slot & 63) << 3;
      us8_t v8 = {0,0,0,0,0,0,0,0};
      int wr = sg0 + s - 1;
      if (wr >= 0) v8 = *(const us8_t*)&out_bf[(bT + wr)*Dn + e8];
      *(us8_t*)&WKh[s*520 + e8] = v8;
    }
    __syncthreads();   // (A) stage visible; also fences PV(j-1)'s PS reads from PS-write below
    f4_t sacc[4];
#pragma unroll
    for (int i = 0; i < 4; ++i) sacc[i] = (f4_t){0.f, 0.f, 0.f, 0.f};
#pragma unroll
    for (int kk = 0; kk < 16; ++kk) {
      const int co = kk*32 + g*8;
#pragma unroll
      for (int nf = 0; nf < 4; ++nf) {
        bf8_t bb = *(const bf8_t*)&WKh[(nf*16 + lr)*520 + co];
        sacc[nf] = MFMA16(rk[kk], bb, sacc[nf]);
      }
    }
    // mask+decay -> PS[t][s]
#pragma unroll
    for (int nf = 0; nf < 4; ++nf) {
#pragma unroll
      for (int r = 0; r < 4; ++r) {
        int tt = w*16 + g*4 + r;
        int ss = nf*16 + lr;
        float df = (float)((qt - j)*64 + tt - ss - 1);
        float mval = (j < qt || tt > ss) ? __builtin_exp2f(l2g * df) : 0.f;
        PS[tt*72 + ss] = f2bf(sacc[nf][r] * mval);
      }
    }
    __syncthreads();   // (B) PS ready
    // PV: A from global vT (L2, XCD-local), B from PS
#pragma unroll
    for (int dh2 = 0; dh2 < 2; ++dh2) {
#pragma unroll
      for (int kk = 0; kk < 2; ++kk) {
        const int co = kk*32 + g*8;
        bf8_t a[4], bb[4];
#pragma unroll
        for (int mf = 0; mf < 4; ++mf)
          a[mf] = *(const bf8_t*)(vbase + (size_t)(dh2*256 + mf*16)*Tn + j*64 + kk*32);
#pragma unroll
        for (int nf = 0; nf < 4; ++nf) bb[nf] = *(const bf8_t*)&PS[(nf*16 + lr)*72 + co];
#pragma unroll
        for (int mf = 0; mf < 4; ++mf)
#pragma unroll
          for (int nf = 0; nf < 4; ++nf)
            acc[dh2][mf][nf] = MFMA16(a[mf], bb[nf], acc[dh2][mf][nf]);
      }
    }
    // no barrier here: next stage touches only WKh (QKT reads done before B);
    // next PS-write is fenced by next (A).
  }

  // epilogue per d-half: transpose acc via WKh scratch -> [t][d], add binter, store
#pragma unroll
  for (int dh2 = 0; dh2 < 2; ++dh2) {
    __syncthreads();
#pragma unroll
    for (int mf = 0; mf < 4; ++mf)
#pragma unroll
      for (int nf = 0; nf < 4; ++nf)
#pragma unroll
        for (int r = 0; r < 4; ++r)
          WKh[(nf*16 + lr)*264 + w*64 + mf*16 + g*4 + r] = f2bf(acc[dh2][mf][nf][r]);
    __syncthreads();
#pragma unroll
    for (int i = 0; i < 8; ++i) {
      int slot = i*256 + tid;
      int t = slot >> 5, d8 = (slot & 31) << 3;
      us8_t ev = *(const us8_t*)&WKh[t*264 + d8];
      us8_t o;
      if (gg > 0) {
        us8_t bv = *(const us8_t*)&binter[(rowbase + t)*Dn + dh2*256 + d8];
#pragma unroll
        for (int k = 0; k < 8; ++k) o[k] = f2bf(bf2f(ev[k]) + bf2f(bv[k]));
      } else {
        o = ev;
      }
      *(us8_t*)&reads_bf[(rowbase + t)*Dn + dh2*256 + d8] = o;
    }
  }
}

// ---------------- K6: out = resid + alpha * (reads @ w_read^T) ----------------
__global__ __launch_bounds__(256) void k_final(const u16* __restrict__ A,
                                               const u16* __restrict__ Bm,
                                               const float* __restrict__ resid,
                                               float* __restrict__ Cout) {
  __shared__ u16 lds[128*72*2];
  u16* As = lds;
  u16* Bs = lds + 128*72;
  const int tid = threadIdx.x;
  const int lane = tid & 63, w = tid >> 6;
  const int g = lane >> 4, lr = lane & 15;
  const int m0 = blockIdx.y * 128, n0 = blockIdx.x * 128;
  const int wm = (w >> 1) * 64, wn = (w & 1) * 64;
  f4_t acc[4][4];
#pragma unroll
  for (int i = 0; i < 4; ++i)
#pragma unroll
    for (int j = 0; j < 4; ++j) acc[i][j] = (f4_t){0.f, 0.f, 0.f, 0.f};

  for (int kb = 0; kb < 8; ++kb) {
    const int k0 = kb * 64;
    __syncthreads();
#pragma unroll
    for (int i = 0; i < 8; ++i) {
      int slot = i * 256 + tid;
      int r = slot >> 4, c4 = (slot & 15) << 2;
      *(us4_t*)&As[r*72 + c4] = *(const us4_t*)&A[(m0 + r)*Dn + k0 + c4];
      *(us4_t*)&Bs[r*72 + c4] = *(const us4_t*)&Bm[(n0 + r)*Dn + k0 + c4];
    }
    __syncthreads();
#pragma unroll
    for (int kk = 0; kk < 2; ++kk) {
      const int co = kk*32 + g*8;
      bf8_t a[4], b[4];
#pragma unroll
      for (int mf = 0; mf < 4; ++mf) a[mf] = *(const bf8_t*)&As[(wm + mf*16 + lr)*72 + co];
#pragma unroll
      for (int nf = 0; nf < 4; ++nf) b[nf] = *(const bf8_t*)&Bs[(wn + nf*16 + lr)*72 + co];
#pragma unroll
      for (int mf = 0; mf < 4; ++mf)
#pragma unroll
        for (int nf = 0; nf < 4; ++nf)
          acc[mf][nf] = MFMA16(a[mf], b[nf], acc[mf][nf]);
    }
  }
#pragma unroll
  for (int mf = 0; mf < 4; ++mf)
#pragma unroll
    for (int nf = 0; nf < 4; ++nf)
#pragma unroll
      for (int r = 0; r < 4; ++r) {
        int row = m0 + wm + mf*16 + g*4 + r;
        int col = n0 + wn + nf*16 + lr;
        int idx = row * Dn + col;
        Cout[idx] = resid[idx] + ALPHAc * acc[mf][nf][r];
      }
}

extern "C" void kernel_launch(void* const* d_in, const int* in_sizes, int n_in,
                              void* d_out, int out_size, void* d_ws, size_t ws_size,
                              hipStream_t stream) {
  const float* out_f   = (const float*)d_in[0];
  const float* w_write = (const float*)d_in[1];
  const float* w_read  = (const float*)d_in[2];
  const float* decay   = (const float*)d_in[3];
  float* outp = (float*)d_out;

  char* ws = (char*)d_ws;
  // NON-ALIASED layout (replay-overlap safe). Total 235,929,600 B.
  u16*   out_bf = (u16*)(ws);
  u16*   wkT    = (u16*)(ws + (size_t)33554432);
  u16*   vT     = (u16*)(ws + (size_t)67108864);
  u16*   wwt_bf = (u16*)(ws + (size_t)100663296);
  u16*   wrd_bf = (u16*)(ws + (size_t)101187584);
  u16*   U      = (u16*)(ws + (size_t)101711872);
  u16*   binter = (u16*)(ws + (size_t)135266304);
  u16*   reads  = (u16*)(ws + (size_t)168820736);
  u16*   Wb     = (u16*)(ws + (size_t)202375168);

  k_convert<<<16384, 256, 0, stream>>>(out_f, out_bf, 4194304);
  k_convert<<<256, 256, 0, stream>>>(w_write, wwt_bf, 65536);
  k_convert<<<256, 256, 0, stream>>>(w_read, wrd_bf, 65536);
  k_wkT<<<dim3(64, 4, 4), 256, 0, stream>>>(out_bf, wkT);
  k_gemm_v<<<dim3(4, 256), 256, 0, stream>>>(out_bf, wwt_bf, vT);
  k_gemm_u<<<dim3(4, 4, 64), 256, 0, stream>>>(vT, wkT, U, decay);
  k_bscan<<<dim3(8, 8, 4), 256, 0, stream>>>(U, Wb, decay);
  k_binter<<<dim3(4, 4, 60), 256, 0, stream>>>(out_bf, Wb, binter, decay);
  k_intra<<<dim3(16, 8, 4), 256, 0, stream>>>(out_bf, vT, binter, reads, decay);
  k_final<<<dim3(4, 256), 256, 0, stream>>>(reads, wrd_bf, out_f, outp);
}